// Round 9
// baseline (634.479 us; speedup 1.0000x reference)
//
#include <hip/hip_runtime.h>
#include <hip/hip_bf16.h>
#include <cmath>

#define T_STEPS 16
#define BATCH   512
#define N_IN    3072
#define S1      256
#define S2      256
#define S3      128
#define NEXP    8
#define M_ROWS  (T_STEPS * BATCH)   // 8192

typedef int v4i  __attribute__((ext_vector_type(4)));
typedef int v16i __attribute__((ext_vector_type(16)));
typedef unsigned long long u64;
typedef unsigned int uint32;

// ---------------------------------------------------------------------------
// pack binary fp32 x -> 1 bit/elem. Output row m' = b*16 + t, 48 u64/row.
// ---------------------------------------------------------------------------
__global__ __launch_bounds__(256) void pack_x_bits(
    const float* __restrict__ x, u64* __restrict__ bits)
{
    int gid = blockIdx.x * 256 + threadIdx.x;
    float v = x[gid];
    u64 m = __ballot(v >= 0.5f);
    if ((threadIdx.x & 63) == 0) {
        int tb = gid / N_IN;                 // t*512 + b
        int k  = gid - tb * N_IN;
        int t  = tb >> 9;
        int b  = tb & 511;
        bits[(size_t)(b * 16 + t) * (N_IN / 64) + (k >> 6)] = m;
    }
}

// ---------------------------------------------------------------------------
// Weight digitize -> MFMA fragment tiles. B-row gr = o*32 + e*4 + limb.
// Bf[kb][nt=o][lane16][16], lane16 = (e*4+limb) + 32*qd, k = kb*32+qd*16+byte.
// One thread per 16-byte chunk (coalesced stores).
// ---------------------------------------------------------------------------
template<int S, int K>
__global__ __launch_bounds__(256) void digitize_w_frag(
    const float* __restrict__ W, char* __restrict__ Bf)
{
    constexpr int LOGS = (S == 256) ? 8 : 7;
    int t = blockIdx.x * 256 + threadIdx.x;   // chunks = 2*S*K
    int lane16 = t & 63;
    int o  = (t >> 6) & (S - 1);
    int kb = t >> (6 + LOGS);
    int r  = lane16 & 31;
    int qd = lane16 >> 5;
    int e    = r >> 2;
    int limb = r & 3;
    int k0 = kb * 32 + qd * 16;

    const float4* Wp = (const float4*)(W + ((size_t)e * S + o) * K + k0);
    char out[16];
    #pragma unroll
    for (int f4 = 0; f4 < 4; ++f4) {
        float4 w = Wp[f4];
        float ws[4] = {w.x, w.y, w.z, w.w};
        #pragma unroll
        for (int c = 0; c < 4; ++c) {
            long long q = llrint((double)ws[c] * 4294967296.0);
            int d = 0;
            #pragma unroll
            for (int l = 0; l < 4; ++l) {
                int dl = (int)((q + 128) & 255) - 128;
                q = (q - dl) >> 8;
                if (l == limb) d = dl;
            }
            out[f4 * 4 + c] = (char)d;
        }
    }
    *(v4i*)(Bf + (size_t)t * 16) = *(v4i*)out;
}

// ---------------------------------------------------------------------------
// Fused expert-GEMM + limb recombine + LIF scan + gated combine + mean.
// Block 128(m') x 128(B-rows), 4 waves 2x2, wave tile 64x64.
// Depth-2 (3-slot) rotating register prefetch for A and B: iter i consumes
// loads issued at iter i-2 (vmcnt waits are partial & covered ~600 cyc).
// Rotation is constant-folded via manual 3x-unrolled bodies (no reg copies).
// launch_bounds(256,3): ~170-reg budget (64 acc AGPR + ~106 VGPR).
// 1-D grid with XCD swizzle: xcd = id&7 owns one n-slab -> B L2-resident.
// ---------------------------------------------------------------------------
template<int K, int S, int SHIFT, bool ABITS, bool WRITEC, int NBLK>
__global__ __launch_bounds__(256, 3) void fused_stage(
    const void* __restrict__ Ap, const char* __restrict__ Bf,
    const float* __restrict__ g, char* __restrict__ C,
    float* __restrict__ Mean)
{
    constexpr int KI = K / 64;
    constexpr int NT = S;                    // number of 32-row n-tiles
    constexpr int NS = NBLK / 8;
    __shared__ double hs[128][32];

    const int tid  = threadIdx.x;
    const int lane = tid & 63;
    const int w    = tid >> 6;
    const int col  = lane & 31;
    const int qd   = lane >> 5;
    const int wm   = (w & 1) * 64;
    const int wn   = (w >> 1) * 64;

    // XCD-swizzled block mapping: id = mblk*NBLK + inner*8 + xcd
    const int id   = blockIdx.x;
    const int nblk = (id & 7) * NS + ((id >> 3) % NS);
    const int mblk = id / NBLK;
    const int m0   = mblk * 128;

    const int nt0 = nblk * 4 + (wn >> 5);
    const char* Bbase = Bf + ((size_t)nt0 * 64 + lane) * 16;

    v16i acc[2][2];
    #pragma unroll
    for (int i = 0; i < 2; ++i)
        #pragma unroll
        for (int j = 0; j < 2; ++j)
            #pragma unroll
            for (int r = 0; r < 16; ++r) acc[i][j][r] = 0;

    const int ar0 = m0 + wm + col;
    const int ar1 = ar0 + 32;

    auto loadB = [&](int kb, int jj) -> v4i {
        return *(const v4i*)(Bbase + (size_t)kb * (NT * 1024) + jj * 1024);
    };

    v4i Bb[3][4];

    if constexpr (ABITS) {
        const u64* A0 = (const u64*)Ap + (size_t)ar0 * KI;
        const u64* A1 = (const u64*)Ap + (size_t)ar1 * KI;
        const int sh16 = qd * 16;
        auto unpack16 = [&](uint32 dw) -> v4i {
            uint32 w16 = dw >> sh16;
            v4i d;
            #pragma unroll
            for (int c = 0; c < 4; ++c)
                d[c] = (int)((((w16 >> (4 * c)) & 0xFu) * 0x00204081u) & 0x01010101u);
            return d;
        };

        u64 a0b[3], a1b[3];
        #pragma unroll
        for (int s = 0; s < 2; ++s) {        // preload iters 0,1 -> slots 0,1
            #pragma unroll
            for (int ks = 0; ks < 2; ++ks)
                #pragma unroll
                for (int jj = 0; jj < 2; ++jj)
                    Bb[s][ks * 2 + jj] = loadB(s * 2 + ks, jj);
            a0b[s] = A0[s];
            a1b[s] = A1[s];
        }

        auto body = [&](int it, int cur, int pf) {
            const int itp = (it + 2 < KI) ? it + 2 : KI - 1;
            #pragma unroll
            for (int ks = 0; ks < 2; ++ks)
                #pragma unroll
                for (int jj = 0; jj < 2; ++jj)
                    Bb[pf][ks * 2 + jj] = loadB(itp * 2 + ks, jj);
            a0b[pf] = A0[itp];
            a1b[pf] = A1[itp];
            #pragma unroll
            for (int ks = 0; ks < 2; ++ks) {
                uint32 dw0 = ks ? (uint32)(a0b[cur] >> 32) : (uint32)a0b[cur];
                uint32 dw1 = ks ? (uint32)(a1b[cur] >> 32) : (uint32)a1b[cur];
                v4i af0 = unpack16(dw0);
                v4i af1 = unpack16(dw1);
                acc[0][0] = __builtin_amdgcn_mfma_i32_32x32x32_i8(af0, Bb[cur][ks*2+0], acc[0][0], 0,0,0);
                acc[0][1] = __builtin_amdgcn_mfma_i32_32x32x32_i8(af0, Bb[cur][ks*2+1], acc[0][1], 0,0,0);
                acc[1][0] = __builtin_amdgcn_mfma_i32_32x32x32_i8(af1, Bb[cur][ks*2+0], acc[1][0], 0,0,0);
                acc[1][1] = __builtin_amdgcn_mfma_i32_32x32x32_i8(af1, Bb[cur][ks*2+1], acc[1][1], 0,0,0);
            }
        };
        static_assert(KI % 3 == 0, "stage-1 KI divisible by 3");
        for (int itb = 0; itb < KI; itb += 3) {
            body(itb + 0, 0, 2);
            body(itb + 1, 1, 0);
            body(itb + 2, 2, 1);
        }
    } else {
        const char* A0 = (const char*)Ap + (size_t)ar0 * K;
        const char* A1 = (const char*)Ap + (size_t)ar1 * K;
        v4i Ab[3][4];
        #pragma unroll
        for (int s = 0; s < 2; ++s) {        // preload iters 0,1 -> slots 0,1
            #pragma unroll
            for (int ks = 0; ks < 2; ++ks) {
                Ab[s][ks * 2 + 0] = *(const v4i*)(A0 + s * 64 + ks * 32 + qd * 16);
                Ab[s][ks * 2 + 1] = *(const v4i*)(A1 + s * 64 + ks * 32 + qd * 16);
                #pragma unroll
                for (int jj = 0; jj < 2; ++jj)
                    Bb[s][ks * 2 + jj] = loadB(s * 2 + ks, jj);
            }
        }
        auto body = [&](int it, int cur, int pf) {
            const int itp = (it + 2 < KI) ? it + 2 : KI - 1;
            #pragma unroll
            for (int ks = 0; ks < 2; ++ks) {
                Ab[pf][ks * 2 + 0] = *(const v4i*)(A0 + itp * 64 + ks * 32 + qd * 16);
                Ab[pf][ks * 2 + 1] = *(const v4i*)(A1 + itp * 64 + ks * 32 + qd * 16);
                #pragma unroll
                for (int jj = 0; jj < 2; ++jj)
                    Bb[pf][ks * 2 + jj] = loadB(itp * 2 + ks, jj);
            }
            #pragma unroll
            for (int ks = 0; ks < 2; ++ks) {
                acc[0][0] = __builtin_amdgcn_mfma_i32_32x32x32_i8(Ab[cur][ks*2+0], Bb[cur][ks*2+0], acc[0][0], 0,0,0);
                acc[0][1] = __builtin_amdgcn_mfma_i32_32x32x32_i8(Ab[cur][ks*2+0], Bb[cur][ks*2+1], acc[0][1], 0,0,0);
                acc[1][0] = __builtin_amdgcn_mfma_i32_32x32x32_i8(Ab[cur][ks*2+1], Bb[cur][ks*2+0], acc[1][0], 0,0,0);
                acc[1][1] = __builtin_amdgcn_mfma_i32_32x32x32_i8(Ab[cur][ks*2+1], Bb[cur][ks*2+1], acc[1][1], 0,0,0);
            }
        };
        static_assert(KI == 4, "stages 2/3 have KI=4");
        body(0, 0, 2);
        body(1, 1, 0);
        body(2, 2, 1);
        body(3, 0, 2);
    }

    // ---- limb recombine (exact, in double) -> LDS h tile ----
    const double sbase = 1.0 / (double)(1ll << SHIFT);
    const int limb = col & 3;
    const double lscale = (double)(1 << (8 * limb)) * sbase;
    #pragma unroll
    for (int j = 0; j < 2; ++j) {
        const int oe = ((wn >> 5) + j) * 8 + (col >> 2);   // o_loc*8 + e
        #pragma unroll
        for (int i = 0; i < 2; ++i) {
            #pragma unroll
            for (int reg = 0; reg < 16; ++reg) {
                double d = (double)acc[i][j][reg] * lscale;
                d += __shfl_xor(d, 1);
                d += __shfl_xor(d, 2);
                if ((col & 3) == 0) {
                    int m = wm + i * 32 + (reg & 3) + 8 * (reg >> 2) + 4 * qd;
                    hs[m][oe] = d;
                }
            }
        }
    }
    __syncthreads();

    // ---- LIF scan: thread = (b_loc = tid>>5, o_loc = (tid>>3)&3, e = tid&7)
    const int b_loc = tid >> 5;
    const int oe    = tid & 31;
    const int e     = tid & 7;
    const float ge  = g[e];
    const int bg = mblk * 8 + b_loc;
    const int og = nblk * 4 + ((tid >> 3) & 3);

    double v = 0.0;
    float gacc = 0.0f;
    #pragma unroll
    for (int t = 0; t < T_STEPS; ++t) {
        double h  = hs[b_loc * 16 + t][oe];
        double vv = v * 0.95 + h;
        int spk = (vv >= 1.0) ? 1 : 0;
        v = vv - (double)spk;
        float gs = ge * (float)spk;
        gs += __shfl_xor(gs, 1);
        gs += __shfl_xor(gs, 2);
        gs += __shfl_xor(gs, 4);
        gacc += gs;
        if (WRITEC) {
            int cnt = spk;
            cnt += __shfl_xor(cnt, 1);
            cnt += __shfl_xor(cnt, 2);
            cnt += __shfl_xor(cnt, 4);
            if (e == 0)
                C[(size_t)(bg * 16 + t) * S + og] = (char)cnt;
        }
    }
    if (e == 0) Mean[(size_t)bg * S + og] = gacc * 0.0625f;
}

// ---------------------------------------------------------------------------
// ws layout (bytes):
//   Abits @ 0          : 3 MB   (8192 x 48 u64, m' = b*16+t)
//   B1f   @ 3145728    : 24 MB
//   B2f   @ 28311552   :  2 MB
//   B3f   @ 30408704   :  1 MB
//   c1    @ 31457280   :  2 MB  (i8 counts, rows m' = b*16+t, 256 cols)
//   c2    @ 33554432   :  2 MB
// ---------------------------------------------------------------------------
extern "C" void kernel_launch(void* const* d_in, const int* in_sizes, int n_in,
                              void* d_out, int out_size, void* d_ws, size_t ws_size,
                              hipStream_t stream) {
    const float* x  = (const float*)d_in[0];
    const float* W1 = (const float*)d_in[1];
    const float* W2 = (const float*)d_in[2];
    const float* W3 = (const float*)d_in[3];
    const float* g1 = (const float*)d_in[4];
    const float* g2 = (const float*)d_in[5];
    const float* g3 = (const float*)d_in[6];
    float* out = (float*)d_out;

    char* ws = (char*)d_ws;
    u64*  Abits = (u64*)ws;
    char* B1f   = ws + 3145728ull;
    char* B2f   = ws + 28311552ull;
    char* B3f   = ws + 30408704ull;
    char* c1    = ws + 31457280ull;
    char* c2    = ws + 33554432ull;

    dim3 blk(256);

    // --- precompute ---
    pack_x_bits<<<(M_ROWS * N_IN) / 256, blk, 0, stream>>>(x, Abits);
    digitize_w_frag<S1, N_IN><<<(2 * S1 * N_IN) / 256, blk, 0, stream>>>(W1, B1f);
    digitize_w_frag<S2, S1><<<(2 * S2 * S1) / 256, blk, 0, stream>>>(W2, B2f);
    digitize_w_frag<S3, S2><<<(2 * S3 * S2) / 256, blk, 0, stream>>>(W3, B3f);

    // --- three fused GEMM+LIF stages, XCD-swizzled 1-D grids ---
    fused_stage<N_IN, S1, 32, true,  true,  64><<<64 * 64, blk, 0, stream>>>(
        Abits, B1f, g1, c1, out);
    fused_stage<S1,   S2, 35, false, true,  64><<<64 * 64, blk, 0, stream>>>(
        c1, B2f, g2, c2, out + BATCH * S1);
    fused_stage<S2,   S3, 35, false, false, 32><<<64 * 32, blk, 0, stream>>>(
        c2, B3f, g3, nullptr, out + BATCH * (S1 + S2));
}

// Round 10
// 539.630 us; speedup vs baseline: 1.1758x; 1.1758x over previous
//
#include <hip/hip_runtime.h>
#include <hip/hip_bf16.h>
#include <cmath>

#define T_STEPS 16
#define BATCH   512
#define N_IN    3072
#define S1      256
#define S2      256
#define S3      128
#define NEXP    8
#define M_ROWS  (T_STEPS * BATCH)   // 8192
#define MT_ALL  (M_ROWS / 32)       // 256 m-tiles

typedef int v4i  __attribute__((ext_vector_type(4)));
typedef int v16i __attribute__((ext_vector_type(16)));
typedef unsigned long long u64;
typedef unsigned int uint32;

// ---------------------------------------------------------------------------
// pack binary fp32 x -> 1 bit/elem, TRANSPOSED: bitsT[kw][m'], m' = b*16+t.
// A-loads in gemm become 32 consecutive u64 (4 lines) instead of 32-line
// gathers (R9 post-mortem).
// ---------------------------------------------------------------------------
__global__ __launch_bounds__(256) void pack_x_bits(
    const float* __restrict__ x, u64* __restrict__ bitsT)
{
    int gid = blockIdx.x * 256 + threadIdx.x;
    float v = x[gid];
    u64 m = __ballot(v >= 0.5f);
    if ((threadIdx.x & 63) == 0) {
        int tb = gid / N_IN;                 // t*512 + b
        int k  = gid - tb * N_IN;
        int t  = tb >> 9;
        int b  = tb & 511;
        bitsT[(size_t)(k >> 6) * M_ROWS + (b * 16 + t)] = m;
    }
}

// ---------------------------------------------------------------------------
// Weight digitize -> MFMA fragment tiles. B-row gr = o*32 + e*4 + limb.
// Bf[kb][nt=o][lane16][16], lane16 = (e*4+limb) + 32*qd, k = kb*32+qd*16+byte.
// ---------------------------------------------------------------------------
template<int S, int K>
__global__ __launch_bounds__(256) void digitize_w_frag(
    const float* __restrict__ W, char* __restrict__ Bf)
{
    constexpr int LOGS = (S == 256) ? 8 : 7;
    int t = blockIdx.x * 256 + threadIdx.x;   // chunks = 2*S*K
    int lane16 = t & 63;
    int o  = (t >> 6) & (S - 1);
    int kb = t >> (6 + LOGS);
    int r  = lane16 & 31;
    int qd = lane16 >> 5;
    int e    = r >> 2;
    int limb = r & 3;
    int k0 = kb * 32 + qd * 16;

    const float4* Wp = (const float4*)(W + ((size_t)e * S + o) * K + k0);
    char out[16];
    #pragma unroll
    for (int f4 = 0; f4 < 4; ++f4) {
        float4 w = Wp[f4];
        float ws[4] = {w.x, w.y, w.z, w.w};
        #pragma unroll
        for (int c = 0; c < 4; ++c) {
            long long q = llrint((double)ws[c] * 4294967296.0);
            int d = 0;
            #pragma unroll
            for (int l = 0; l < 4; ++l) {
                int dl = (int)((q + 128) & 255) - 128;
                q = (q - dl) >> 8;
                if (l == limb) d = dl;
            }
            out[f4 * 4 + c] = (char)d;
        }
    }
    *(v4i*)(Bf + (size_t)t * 16) = *(v4i*)out;
}

// ---------------------------------------------------------------------------
// Fused expert-GEMM + limb recombine + LIF + gated combine + mean.
// Block 256(m') x 64(B-rows): 4 waves stacked in m, ALL waves share identical
// B-fragment addresses (L1 hits for trailing waves). Wave tile 64x64.
// A: ABITS ? transposed bit rows (contiguous 256B loads) : fragment-tile
// counts (contiguous 1KB loads, same form as B).
// Counts OUTPUT is also fragment-tile layout (k = this stage's o).
// 1-D grid, XCD swizzle: xcd = id&7 owns one n-slab -> B L2-resident.
// ---------------------------------------------------------------------------
template<int K, int S, int SHIFT, bool ABITS, bool WRITEC, int NBLK>
__global__ __launch_bounds__(256, 3) void fused_stage(
    const void* __restrict__ Ap, const char* __restrict__ Bf,
    const float* __restrict__ g, char* __restrict__ Cf,
    float* __restrict__ Mean)
{
    constexpr int KI = K / 64;
    constexpr int NT = S;                    // 32-row n-tiles in Bf
    constexpr int NS = NBLK / 8;
    __shared__ double hs[256][16];

    const int tid  = threadIdx.x;
    const int lane = tid & 63;
    const int w    = tid >> 6;
    const int col  = lane & 31;
    const int qd   = lane >> 5;
    const int wm   = w * 64;

    // XCD-swizzled block mapping: id = mblk*NBLK + inner*8 + xcd
    const int id   = blockIdx.x;
    const int nblk = (id & 7) * NS + ((id >> 3) % NS);
    const int mblk = id / NBLK;
    const int m0   = mblk * 256;

    const int nt0 = nblk * 2;
    const char* Bbase = Bf + ((size_t)nt0 * 64 + lane) * 16;

    v16i acc[2][2];
    #pragma unroll
    for (int i = 0; i < 2; ++i)
        #pragma unroll
        for (int j = 0; j < 2; ++j)
            #pragma unroll
            for (int r = 0; r < 16; ++r) acc[i][j][r] = 0;

    auto loadB = [&](int kb, int jj) -> v4i {
        return *(const v4i*)(Bbase + (size_t)kb * (NT * 1024) + jj * 1024);
    };

    v4i Bb[3][4];

    if constexpr (ABITS) {
        // transposed bits: AT[it][m'], contiguous in m'
        const u64* AT = (const u64*)Ap + (m0 + wm + col);
        const int sh16 = qd * 16;
        auto unpack16 = [&](uint32 dw) -> v4i {
            uint32 w16 = dw >> sh16;
            v4i d;
            #pragma unroll
            for (int c = 0; c < 4; ++c)
                d[c] = (int)((((w16 >> (4 * c)) & 0xFu) * 0x00204081u) & 0x01010101u);
            return d;
        };
        u64 a0b[3], a1b[3];
        #pragma unroll
        for (int s = 0; s < 2; ++s) {
            #pragma unroll
            for (int ks = 0; ks < 2; ++ks)
                #pragma unroll
                for (int jj = 0; jj < 2; ++jj)
                    Bb[s][ks * 2 + jj] = loadB(s * 2 + ks, jj);
            a0b[s] = AT[(size_t)s * M_ROWS];
            a1b[s] = AT[(size_t)s * M_ROWS + 32];
        }
        auto body = [&](int it, int cur, int pf) {
            const int itp = (it + 2 < KI) ? it + 2 : KI - 1;
            #pragma unroll
            for (int ks = 0; ks < 2; ++ks)
                #pragma unroll
                for (int jj = 0; jj < 2; ++jj)
                    Bb[pf][ks * 2 + jj] = loadB(itp * 2 + ks, jj);
            a0b[pf] = AT[(size_t)itp * M_ROWS];
            a1b[pf] = AT[(size_t)itp * M_ROWS + 32];
            #pragma unroll
            for (int ks = 0; ks < 2; ++ks) {
                uint32 dw0 = ks ? (uint32)(a0b[cur] >> 32) : (uint32)a0b[cur];
                uint32 dw1 = ks ? (uint32)(a1b[cur] >> 32) : (uint32)a1b[cur];
                v4i af0 = unpack16(dw0);
                v4i af1 = unpack16(dw1);
                acc[0][0] = __builtin_amdgcn_mfma_i32_32x32x32_i8(af0, Bb[cur][ks*2+0], acc[0][0], 0,0,0);
                acc[0][1] = __builtin_amdgcn_mfma_i32_32x32x32_i8(af0, Bb[cur][ks*2+1], acc[0][1], 0,0,0);
                acc[1][0] = __builtin_amdgcn_mfma_i32_32x32x32_i8(af1, Bb[cur][ks*2+0], acc[1][0], 0,0,0);
                acc[1][1] = __builtin_amdgcn_mfma_i32_32x32x32_i8(af1, Bb[cur][ks*2+1], acc[1][1], 0,0,0);
            }
        };
        static_assert(KI % 3 == 0, "stage-1 KI divisible by 3");
        for (int itb = 0; itb < KI; itb += 3) {
            body(itb + 0, 0, 2);
            body(itb + 1, 1, 0);
            body(itb + 2, 2, 1);
        }
    } else {
        // A in fragment-tile layout: Af[kb][mt][lane][16]
        const int mt0 = (m0 + wm) >> 5;
        const char* Abase = (const char*)Ap + ((size_t)mt0 * 64 + lane) * 16;
        auto loadA = [&](int kb, int ii) -> v4i {
            return *(const v4i*)(Abase + (size_t)kb * (MT_ALL * 1024) + ii * 1024);
        };
        v4i Ab[3][4];
        #pragma unroll
        for (int s = 0; s < 2; ++s) {
            #pragma unroll
            for (int ks = 0; ks < 2; ++ks) {
                Ab[s][ks * 2 + 0] = loadA(s * 2 + ks, 0);
                Ab[s][ks * 2 + 1] = loadA(s * 2 + ks, 1);
                #pragma unroll
                for (int jj = 0; jj < 2; ++jj)
                    Bb[s][ks * 2 + jj] = loadB(s * 2 + ks, jj);
            }
        }
        auto body = [&](int it, int cur, int pf) {
            const int itp = (it + 2 < KI) ? it + 2 : KI - 1;
            #pragma unroll
            for (int ks = 0; ks < 2; ++ks) {
                Ab[pf][ks * 2 + 0] = loadA(itp * 2 + ks, 0);
                Ab[pf][ks * 2 + 1] = loadA(itp * 2 + ks, 1);
                #pragma unroll
                for (int jj = 0; jj < 2; ++jj)
                    Bb[pf][ks * 2 + jj] = loadB(itp * 2 + ks, jj);
            }
            #pragma unroll
            for (int ks = 0; ks < 2; ++ks) {
                acc[0][0] = __builtin_amdgcn_mfma_i32_32x32x32_i8(Ab[cur][ks*2+0], Bb[cur][ks*2+0], acc[0][0], 0,0,0);
                acc[0][1] = __builtin_amdgcn_mfma_i32_32x32x32_i8(Ab[cur][ks*2+0], Bb[cur][ks*2+1], acc[0][1], 0,0,0);
                acc[1][0] = __builtin_amdgcn_mfma_i32_32x32x32_i8(Ab[cur][ks*2+1], Bb[cur][ks*2+0], acc[1][0], 0,0,0);
                acc[1][1] = __builtin_amdgcn_mfma_i32_32x32x32_i8(Ab[cur][ks*2+1], Bb[cur][ks*2+1], acc[1][1], 0,0,0);
            }
        };
        static_assert(KI == 4, "stages 2/3 have KI=4");
        body(0, 0, 2);
        body(1, 1, 0);
        body(2, 2, 1);
        body(3, 0, 2);
    }

    // ---- limb recombine (exact, in double) -> LDS h tile ----
    const double sbase = 1.0 / (double)(1ll << SHIFT);
    const int limb = col & 3;
    const double lscale = (double)(1 << (8 * limb)) * sbase;
    #pragma unroll
    for (int j = 0; j < 2; ++j) {
        const int oe = j * 8 + (col >> 2);            // o_loc*8 + e
        #pragma unroll
        for (int i = 0; i < 2; ++i) {
            #pragma unroll
            for (int reg = 0; reg < 16; ++reg) {
                double d = (double)acc[i][j][reg] * lscale;
                d += __shfl_xor(d, 1);
                d += __shfl_xor(d, 2);
                if ((col & 3) == 0) {
                    int m = wm + i * 32 + (reg & 3) + 8 * (reg >> 2) + 4 * qd;
                    hs[m][oe] = d;
                }
            }
        }
    }
    __syncthreads();

    // ---- LIF scan: thread = (b_loc = tid>>4, o_loc = (tid>>3)&1, e = tid&7)
    const int b_loc  = tid >> 4;
    const int o_loc  = (tid >> 3) & 1;
    const int e      = tid & 7;
    const int oe     = o_loc * 8 + e;
    const float ge   = g[e];
    const int bg = mblk * 16 + b_loc;
    const int og = nblk * 2 + o_loc;

    // fragment-tile write coords for counts (k = og of this stage)
    const int kb_a   = og >> 5;
    const int qd_a   = (og >> 4) & 1;
    const int byte_a = og & 15;

    double v = 0.0;
    float gacc = 0.0f;
    #pragma unroll
    for (int t = 0; t < T_STEPS; ++t) {
        double h  = hs[b_loc * 16 + t][oe];
        double vv = v * 0.95 + h;
        int spk = (vv >= 1.0) ? 1 : 0;
        v = vv - (double)spk;
        float gs = ge * (float)spk;
        gs += __shfl_xor(gs, 1);
        gs += __shfl_xor(gs, 2);
        gs += __shfl_xor(gs, 4);
        gacc += gs;
        if (WRITEC) {
            int cnt = spk;
            cnt += __shfl_xor(cnt, 1);
            cnt += __shfl_xor(cnt, 2);
            cnt += __shfl_xor(cnt, 4);
            if (e == 0) {
                int mp = bg * 16 + t;
                int lane_a = (mp & 31) + 32 * qd_a;
                Cf[(((size_t)kb_a * MT_ALL + (mp >> 5)) * 64 + lane_a) * 16 + byte_a]
                    = (char)cnt;
            }
        }
    }
    if (e == 0) Mean[(size_t)bg * S + og] = gacc * 0.0625f;
}

// ---------------------------------------------------------------------------
// ws layout (bytes):
//   AbitsT @ 0          : 3 MB   (48 x 8192 u64, transposed)
//   B1f    @ 3145728    : 24 MB
//   B2f    @ 28311552   :  2 MB
//   B3f    @ 30408704   :  1 MB
//   c1f    @ 31457280   :  2 MB  (frag-tile counts, K=256)
//   c2f    @ 33554432   :  2 MB
// ---------------------------------------------------------------------------
extern "C" void kernel_launch(void* const* d_in, const int* in_sizes, int n_in,
                              void* d_out, int out_size, void* d_ws, size_t ws_size,
                              hipStream_t stream) {
    const float* x  = (const float*)d_in[0];
    const float* W1 = (const float*)d_in[1];
    const float* W2 = (const float*)d_in[2];
    const float* W3 = (const float*)d_in[3];
    const float* g1 = (const float*)d_in[4];
    const float* g2 = (const float*)d_in[5];
    const float* g3 = (const float*)d_in[6];
    float* out = (float*)d_out;

    char* ws = (char*)d_ws;
    u64*  AbitsT = (u64*)ws;
    char* B1f    = ws + 3145728ull;
    char* B2f    = ws + 28311552ull;
    char* B3f    = ws + 30408704ull;
    char* c1f    = ws + 31457280ull;
    char* c2f    = ws + 33554432ull;

    dim3 blk(256);

    // --- precompute ---
    pack_x_bits<<<(M_ROWS * N_IN) / 256, blk, 0, stream>>>(x, AbitsT);
    digitize_w_frag<S1, N_IN><<<(2 * S1 * N_IN) / 256, blk, 0, stream>>>(W1, B1f);
    digitize_w_frag<S2, S1><<<(2 * S2 * S1) / 256, blk, 0, stream>>>(W2, B2f);
    digitize_w_frag<S3, S2><<<(2 * S3 * S2) / 256, blk, 0, stream>>>(W3, B3f);

    // --- three fused GEMM+LIF stages, XCD-swizzled 1-D grids ---
    // grids: mblk = 8192/256 = 32; nblk = (S*32)/64
    fused_stage<N_IN, S1, 32, true,  true,  128><<<32 * 128, blk, 0, stream>>>(
        AbitsT, B1f, g1, c1f, out);
    fused_stage<S1,   S2, 35, false, true,  128><<<32 * 128, blk, 0, stream>>>(
        c1f, B2f, g2, c2f, out + BATCH * S1);
    fused_stage<S2,   S3, 35, false, false, 64><<<32 * 64, blk, 0, stream>>>(
        c2f, B3f, g3, nullptr, out + BATCH * (S1 + S2));
}